// Round 8
// baseline (735.943 us; speedup 1.0000x reference)
//
#include <hip/hip_runtime.h>
#include <hip/hip_bf16.h>
#include <stdint.h>

namespace {

constexpr int D    = 512;
constexpr int S    = 1536;
constexpr int N    = S + 1;      // 1537
constexpr int L    = 4;
constexpr int H    = 4;
constexpr int R    = 32;
constexpr int W    = 128;
constexpr int HFF  = 1024;
constexpr float EPS = 1e-5f;

// attention: 4 tokens/block, shared neighbor span
constexpr int TB   = 4;
constexpr int NB4  = (N + TB - 1) / TB;   // 385 blocks
constexpr int SP   = 133;    // c=0..131 window span (g = n0-W+c), c=132 anchor
constexpr int SPAD = 137;    // padded row stride (2-way bank alias)

constexpr int GS2  = 1024;   // setup kernel grid
constexpr int SLABR = 528;   // gemm64 slab stride: 64 rows * 8 ushorts + 16 pad
constexpr int BK   = 128;    // gemm64 K-step

// mega kernel LDS layout (bytes); total 48080 = R6's attn size -> 3 blocks/CU
// floats: kg 0..8768 | qsh 8768..9280 | ssh 9280..11472 | ash 11472..12020
// aliases into dead regions:
//   xbuf  = kg floats 0..2080 (after scores)
//   val1s = floats 8768..10848 (over qsh+ssh, dead after softmax), stride 520
//   x2s   = bytes  8320..12544 (kg floats 2080..3136), 4 rows * 528 us
//   hs    = bytes 12544..20864, 4 rows * 1040 us
//   v0s   = bytes 20864..25088, 4 rows * 528 us
constexpr int SMB = 48080;

typedef __attribute__((ext_vector_type(8))) short short8;
typedef __attribute__((ext_vector_type(4))) float floatx4;

__device__ inline ushort f2bf(float x){
  __hip_bfloat16 h = __float2bfloat16(x);
  return *reinterpret_cast<ushort*>(&h);
}
__device__ inline float bf2f(uint u){
  union { uint u; float f; } c; c.u = u << 16; return c.f;
}

// ---------------- reductions ------------------------------------------------
__device__ inline float wave_sum(float v){
#pragma unroll
  for (int o = 32; o; o >>= 1) v += __shfl_xor(v, o, 64);
  return v;
}
__device__ inline float wave_max(float v){
#pragma unroll
  for (int o = 32; o; o >>= 1) v = fmaxf(v, __shfl_xor(v, o, 64));
  return v;
}
__device__ inline float block_sum(float v, float* scr){
  v = wave_sum(v);
  __syncthreads();
  if ((threadIdx.x & 63) == 0) scr[threadIdx.x >> 6] = v;
  __syncthreads();
  return scr[0] + scr[1] + scr[2] + scr[3];
}

// ---------------- fused setup: embed+LN+state | pack wqk | transpose ffn ----
__global__ __launch_bounds__(256) void setup_kernel(
    const int* __restrict__ ids, const float* __restrict__ embed,
    const float* __restrict__ pos, const float* __restrict__ g,
    const float* __restrict__ b, const float* __restrict__ anchor_val,
    const float* __restrict__ anchor_state, const float* __restrict__ state_w,
    const float* __restrict__ state_b, float* __restrict__ val,
    ushort* __restrict__ valbf, float* __restrict__ state,
    const float* __restrict__ wq, const float* __restrict__ wk,
    ushort* __restrict__ wqkbf,
    const float* __restrict__ ffn_w1, const float* __restrict__ ffn_w2,
    ushort* __restrict__ w1t, ushort* __restrict__ w2t)
{
  __shared__ float scr[4];
  __shared__ float tile[32 * 33];
  const int t = threadIdx.x;

  for (int n = blockIdx.x; n < N; n += GS2){
    if (n == 0){
      float a0 = anchor_val[t], a1 = anchor_val[t + 256];
      val[t] = a0; val[t + 256] = a1;
      valbf[t] = f2bf(a0); valbf[t + 256] = f2bf(a1);
      if (t == 0) state[0] = anchor_state[0];
      continue;
    }
    int tp = n - 1;
    int id = ids[tp];
    float x0 = embed[(size_t)id * D + t]       + pos[tp * D + t];
    float x1 = embed[(size_t)id * D + t + 256] + pos[tp * D + t + 256];
    float mean = block_sum(x0 + x1, scr) * (1.f / D);
    float var  = block_sum(x0 * x0 + x1 * x1, scr) * (1.f / D) - mean * mean;
    float rs   = rsqrtf(var + EPS);
    float y0 = (x0 - mean) * rs * g[t]       + b[t];
    float y1 = (x1 - mean) * rs * g[t + 256] + b[t + 256];
    val[n * D + t]       = y0;
    val[n * D + t + 256] = y1;
    valbf[n * D + t]       = f2bf(y0);
    valbf[n * D + t + 256] = f2bf(y1);
    float ts = block_sum(y0 * state_w[t] + y1 * state_w[t + 256], scr);
    if (t == 0) state[n] = ts + state_b[0];
  }

  for (int i = blockIdx.x * 256 + t; i < L * 256 * D; i += GS2 * 256){
    int d = i & 511;
    int c = (i >> 9) & 255;
    int l = i >> 17;
    int cc = c & 127;
    int h = cc >> 5, r = cc & 31;
    const float* src = (c < 128) ? wq : wk;
    wqkbf[i] = f2bf(src[((l * H + h) * D + d) * R + r]);
  }
  __syncthreads();

  const int tx = t & 31, ty = t >> 5;
  for (int tl = blockIdx.x; tl < 2 * L * 512; tl += GS2){
    const float* s; ushort* dd; int rows, cols, c0, r0;
    if (tl < 2048){
      int ll = tl >> 9, i = tl & 511;
      rows = D; cols = HFF;
      s  = ffn_w1 + (size_t)ll * D * HFF;
      dd = w1t   + (size_t)ll * D * HFF;
      c0 = (i & 31) << 5; r0 = (i >> 5) << 5;
    } else {
      int tl2 = tl - 2048;
      int ll = tl2 >> 9, i = tl2 & 511;
      rows = HFF; cols = D;
      s  = ffn_w2 + (size_t)ll * D * HFF;
      dd = w2t   + (size_t)ll * D * HFF;
      c0 = (i & 15) << 5; r0 = (i >> 4) << 5;
    }
    __syncthreads();
    for (int rr = ty; rr < 32; rr += 8)
      tile[rr * 33 + tx] = s[(size_t)(r0 + rr) * cols + c0 + tx];
    __syncthreads();
    for (int rr = ty; rr < 32; rr += 8)
      dd[(size_t)(c0 + rr) * rows + r0 + tx] = f2bf(tile[tx * 33 + rr]);
  }
}

// ---------------- bf16 MFMA GEMM, 64x64 tile, BK=128, 2-phase pipelined -----
// (R6-verified) C = act(A*Bt^T + bias)(+resid). Used only for layer-0 QK now.
template<int ACT>
__global__ __launch_bounds__(256) void gemm64(
    const ushort* __restrict__ A, const ushort* __restrict__ Bt,
    const float* __restrict__ bias, const float* __restrict__ resid,
    float* __restrict__ C, ushort* __restrict__ Cbf,
    int M, int Kd, int Nc)
{
  __shared__ ushort As[16 * SLABR];
  __shared__ ushort Bs[16 * SLABR];
  const int row0 = blockIdx.y * 64;
  const int col0 = blockIdx.x * 64;
  const int t = threadIdx.x;
  const int lane = t & 63, w = t >> 6;
  const int wr = w & 1, wc = w >> 1;
  const int q = lane >> 4, lm = lane & 15;

  const int srow = t >> 3, skb = t & 7;
  int ar0 = min(row0 + srow,      M - 1);
  int ar1 = min(row0 + srow + 32, M - 1);
  const ushort* agA0 = A  + (size_t)ar0 * Kd + skb * 8;
  const ushort* agA1 = A  + (size_t)ar1 * Kd + skb * 8;
  const ushort* agB0 = Bt + (size_t)(col0 + srow) * Kd + skb * 8;
  const ushort* agB1 = Bt + (size_t)(col0 + srow + 32) * Kd + skb * 8;
  ushort* asw00 = &As[ skb      * SLABR +  srow       * 8];
  ushort* asw01 = &As[(skb + 8) * SLABR +  srow       * 8];
  ushort* asw10 = &As[ skb      * SLABR + (srow + 32) * 8];
  ushort* asw11 = &As[(skb + 8) * SLABR + (srow + 32) * 8];
  ushort* bsw00 = &Bs[ skb      * SLABR +  srow       * 8];
  ushort* bsw01 = &Bs[(skb + 8) * SLABR +  srow       * 8];
  ushort* bsw10 = &Bs[ skb      * SLABR + (srow + 32) * 8];
  ushort* bsw11 = &Bs[(skb + 8) * SLABR + (srow + 32) * 8];

  const ushort* arp = &As[(wr * 32 + lm) * 8];
  const ushort* brp = &Bs[(wc * 32 + lm) * 8];

  floatx4 acc[2][2];
#pragma unroll
  for (int m = 0; m < 2; ++m)
#pragma unroll
    for (int n = 0; n < 2; ++n) acc[m][n] = {0.f, 0.f, 0.f, 0.f};

  const int nk0 = Kd / BK;
  uint4 pa0, pa1, pa2, pa3, pb0, pb1, pb2, pb3;
  pa0 = *(const uint4*)(agA0);      pa1 = *(const uint4*)(agA0 + 64);
  pa2 = *(const uint4*)(agA1);      pa3 = *(const uint4*)(agA1 + 64);
  pb0 = *(const uint4*)(agB0);      pb1 = *(const uint4*)(agB0 + 64);
  pb2 = *(const uint4*)(agB1);      pb3 = *(const uint4*)(agB1 + 64);

  for (int i = 0; i < nk0; ++i){
    *(uint4*)asw00 = pa0; *(uint4*)asw01 = pa1;
    *(uint4*)asw10 = pa2; *(uint4*)asw11 = pa3;
    *(uint4*)bsw00 = pb0; *(uint4*)bsw01 = pb1;
    *(uint4*)bsw10 = pb2; *(uint4*)bsw11 = pb3;
    __syncthreads();
    if (i + 1 < nk0){
      const int ko = (i + 1) * BK;
      pa0 = *(const uint4*)(agA0 + ko);      pa1 = *(const uint4*)(agA0 + ko + 64);
      pa2 = *(const uint4*)(agA1 + ko);      pa3 = *(const uint4*)(agA1 + ko + 64);
      pb0 = *(const uint4*)(agB0 + ko);      pb1 = *(const uint4*)(agB0 + ko + 64);
      pb2 = *(const uint4*)(agB1 + ko);      pb3 = *(const uint4*)(agB1 + ko + 64);
    }
#pragma unroll
    for (int kk = 0; kk < 4; ++kk){
      const int kb = (kk * 4 + q) * SLABR;
      short8 am0 = *(const short8*)(arp + kb);
      short8 am1 = *(const short8*)(arp + kb + 16 * 8);
      short8 bn0 = *(const short8*)(brp + kb);
      short8 bn1 = *(const short8*)(brp + kb + 16 * 8);
      acc[0][0] = __builtin_amdgcn_mfma_f32_16x16x32_bf16(am0, bn0, acc[0][0], 0, 0, 0);
      acc[0][1] = __builtin_amdgcn_mfma_f32_16x16x32_bf16(am0, bn1, acc[0][1], 0, 0, 0);
      acc[1][0] = __builtin_amdgcn_mfma_f32_16x16x32_bf16(am1, bn0, acc[1][0], 0, 0, 0);
      acc[1][1] = __builtin_amdgcn_mfma_f32_16x16x32_bf16(am1, bn1, acc[1][1], 0, 0, 0);
    }
    __syncthreads();
  }

#pragma unroll
  for (int m = 0; m < 2; ++m){
#pragma unroll
    for (int n = 0; n < 2; ++n){
      int col = col0 + wc * 32 + n * 16 + lm;
#pragma unroll
      for (int r = 0; r < 4; ++r){
        int row = row0 + wr * 32 + m * 16 + q * 4 + r;
        if (row >= M) continue;
        float v = acc[m][n][r] + (bias ? bias[col] : 0.f);
        if (ACT == 1) v = 0.5f * v * (1.f + erff(v * 0.70710678118654752f));
        if (resid) v += resid[(size_t)row * Nc + col];
        size_t o = (size_t)row * Nc + col;
        if (C)   C[o] = v;
        if (Cbf) Cbf[o] = f2bf(v);
      }
    }
  }
}

// ---------------- mega layer kernel: attn + LN + FFN1 + FFN2 + next-QK ------
// One dispatch per layer. attn block-structure identical to R6's verified
// attn4; FFN1/FFN2/qk-next are row-local skinny GEMMs: A (4 rows, replicated
// to 16 via lm&3) in LDS, B fragments read directly from global (L2-resident
// weights), identical k-order to gemm64 -> bitwise-identical accumulation.
// No redundant work (R7 lesson: halo recompute loses; row-local fusion wins).
__global__ __launch_bounds__(256) void mega_kernel(
    const ushort* __restrict__ qkc,      // this layer's qk [N][256]
    const ushort* __restrict__ wqkn,     // next layer wqk [256][512] (null if last)
    const float* __restrict__ val0,      // layer input f32 (residual)
    const ushort* __restrict__ val0bf,   // layer input bf16
    const float* __restrict__ state_in,
    float* __restrict__ dstf,            // next val0 f32 OR final out
    ushort* __restrict__ v0bfn,          // next val0 bf16 (null if last)
    ushort* __restrict__ qkn,            // next qk (null if last)
    float* __restrict__ state_out,
    const float* __restrict__ gate_p, const float* __restrict__ lng,
    const float* __restrict__ lnb, const float* __restrict__ ln2g,
    const float* __restrict__ ln2b,
    const float* __restrict__ b1p, const float* __restrict__ b2p,
    const ushort* __restrict__ w1l, const ushort* __restrict__ w2l,
    int last)
{
  __shared__ __align__(16) char SM[SMB];
  float* SMf = (float*)SM;
  float* kg  = SMf;                 // [64][SPAD]
  float* qsh = SMf + 8768;          // [TB*128]
  float* ssh = SMf + 9280;          // [16][SPAD]
  float* ash = SMf + 11472;         // [TB][SPAD]
  float* val1s = SMf + 8768;        // alias (post-softmax), stride 520
  ushort* x2u = (ushort*)(SM + 8320);    // [4][528]
  ushort* hsu = (ushort*)(SM + 12544);   // [4][1040]
  ushort* v0u = (ushort*)(SM + 20864);   // [4][528]

  const int n0 = blockIdx.x * TB;
  const int t = threadIdx.x;
  const int w = t >> 6, l = t & 63;   // wave = token index
  const int q = l >> 4, lm = l & 15;  // mfma lane decomposition
  const int arow = lm & 3;            // row-replicated A reads
  const float gate = gate_p[0];
  const float scale = 0.17677669529663687f;  // 1/sqrt(32)

  // ---- stage q (4 tokens x 128 ch)
#pragma unroll
  for (int i = t; i < TB * 128; i += 256){
    int it = i >> 7, ch = i & 127;
    int gr = min(n0 + it, N - 1);
    qsh[i] = bf2f((uint)qkc[(size_t)gr * 256 + ch]);
  }

  // ---- scores, two halves of 64 channels
  for (int half = 0; half < 2; ++half){
    for (int i = t; i < SP * 16; i += 256){
      int c = i >> 4, c4 = i & 15;
      int g = (c == 132) ? 0 : min(max(n0 - W + c, 0), N - 1);
      uint2 v = *(const uint2*)&qkc[(size_t)g * 256 + 128 + half * 64 + c4 * 4];
      int ch = c4 * 4;
      kg[(ch + 0) * SPAD + c] = bf2f(v.x & 0xffffu);
      kg[(ch + 1) * SPAD + c] = bf2f(v.x >> 16);
      kg[(ch + 2) * SPAD + c] = bf2f(v.y & 0xffffu);
      kg[(ch + 3) * SPAD + c] = bf2f(v.y >> 16);
    }
    __syncthreads();
    for (int tk = t; tk < TB * 2 * SP; tk += 256){
      int c = tk % SP;
      int th = tk / SP;            // 0..7
      int tok = th & 3, hh = th >> 2;
      int h = half * 2 + hh;
      const float* qs = &qsh[tok * 128 + h * 32];
      const float* ks = &kg[hh * 32 * SPAD + c];
      float acc = 0.f;
#pragma unroll
      for (int r = 0; r < 32; ++r) acc += qs[r] * ks[r * SPAD];
      ssh[(tok * 4 + h) * SPAD + c] = acc * scale;
    }
    __syncthreads();
  }

  // ---- per-(tok,c) head softmax -> a
  for (int i = t; i < TB * SP; i += 256){
    int tok = i / SP, c = i - tok * SP;
    const float* sr = &ssh[tok * 4 * SPAD + c];
    float s0 = sr[0], s1 = sr[SPAD], s2 = sr[2 * SPAD], s3 = sr[3 * SPAD];
    float a0 = fabsf(s0), a1 = fabsf(s1), a2 = fabsf(s2), a3 = fabsf(s3);
    float m = fmaxf(fmaxf(a0, a1), fmaxf(a2, a3));
    float w0 = expf(a0 - m), w1 = expf(a1 - m), w2 = expf(a2 - m), w3 = expf(a3 - m);
    ash[tok * SPAD + c] = (s0 * w0 + s1 * w1 + s2 * w2 + s3 * w3) / (w0 + w1 + w2 + w3);
  }
  __syncthreads();

  // ---- per-token signed softmax over span (wave w <-> token w), e in place
  {
    const int n = n0 + w;
    float* arw = &ash[w * SPAD];
    float a0 = arw[l];
    float a1 = arw[64 + l];
    float a2 = (l < 5) ? arw[128 + l] : 0.f;
    bool ok0 = (l >= w) && (n0 - W + l >= 0);
    bool ok1 = (n0 - W + 64 + l >= 0);
    bool ok2;
    if (l < 4)       ok2 = (l <= w);
    else if (l == 4) ok2 = (n > W);
    else             ok2 = false;
    float cand = -3.4e38f;
    if (ok0) cand = fabsf(a0);
    if (ok1) cand = fmaxf(cand, fabsf(a1));
    if (ok2) cand = fmaxf(cand, fabsf(a2));
    float m = wave_max(cand);
    float e0 = ok0 ? expf(fabsf(a0) - m) : 0.f;
    float e1 = ok1 ? expf(fabsf(a1) - m) : 0.f;
    float e2 = ok2 ? expf(fabsf(a2) - m) : 0.f;
    float inv = 1.f / wave_sum(e0 + e1 + e2);
    int g0 = min(max(n0 - W + l, 0), N - 1);
    int g1 = min(max(n0 - W + 64 + l, 0), N - 1);
    int g2 = (l < 4) ? min(n0 + l, N - 1) : 0;
    float sg0 = (a0 > 0.f) ? 1.f : ((a0 < 0.f) ? -1.f : 0.f);
    float sg1 = (a1 > 0.f) ? 1.f : ((a1 < 0.f) ? -1.f : 0.f);
    float sg2 = (a2 > 0.f) ? 1.f : ((a2 < 0.f) ? -1.f : 0.f);
    float t0 = sg0 * e0 * inv * state_in[g0];
    float t1 = sg1 * e1 * inv * state_in[g1];
    float t2 = (l < 5) ? sg2 * e2 * inv * state_in[g2] : 0.f;
    arw[l] = t0;
    arw[64 + l] = t1;
    if (l < 5) arw[128 + l] = t2;
    float ds = wave_sum(t0 + t1 + t2);
    if (l == 0 && n < N) state_out[n] = state_in[n] + gate * ds;
  }
  __syncthreads();

  // ---- d_val: stream span rows once (bf16), 4 accumulators per thread
  float acc[TB][2];
#pragma unroll
  for (int k = 0; k < TB; ++k){ acc[k][0] = 0.f; acc[k][1] = 0.f; }
  {
    const int d0 = 2 * t;
    for (int c = 0; c < SP; ++c){
      int g = (c == 132) ? 0 : min(max(n0 - W + c, 0), N - 1);
      uint v = *(const uint*)&val0bf[(size_t)g * D + d0];
      float vx = bf2f(v & 0xffffu), vy = bf2f(v >> 16);
#pragma unroll
      for (int k = 0; k < TB; ++k){
        float e = ash[k * SPAD + c];
        acc[k][0] += e * vx;
        acc[k][1] += e * vy;
      }
    }
  }
  // residual into xbuf (reuse kg; kg dead after scores)
  float* xbuf = kg;    // [4][520]
  {
    const int d0 = 2 * t;
#pragma unroll
    for (int k = 0; k < TB; ++k){
      int nc = min(n0 + k, N - 1);
      float2 vv = *(const float2*)&val0[(size_t)nc * D + d0];
      xbuf[k * 520 + d0]     = vv.x + gate * acc[k][0];
      xbuf[k * 520 + d0 + 1] = vv.y + gate * acc[k][1];
    }
  }
  __syncthreads();

  // ---- LN1 -> val1s (LDS), LN2 -> x2s (LDS bf16); wave per token
  {
    const int d = l * 8;
    const float* xr = &xbuf[w * 520 + d];
    float x[8];
#pragma unroll
    for (int j = 0; j < 8; ++j) x[j] = xr[j];
    float s1 = 0.f, s2 = 0.f;
#pragma unroll
    for (int j = 0; j < 8; ++j){ s1 += x[j]; s2 += x[j] * x[j]; }
    s1 = wave_sum(s1); s2 = wave_sum(s2);
    float mean = s1 * (1.f / D);
    float var  = s2 * (1.f / D) - mean * mean;
    float rs   = rsqrtf(var + EPS);
    float y[8];
    float u1 = 0.f, u2 = 0.f;
#pragma unroll
    for (int j = 0; j < 8; ++j){
      float yv = (x[j] - mean) * rs * lng[d + j] + lnb[d + j];
      y[j] = yv; u1 += yv; u2 += yv * yv;
    }
    u1 = wave_sum(u1); u2 = wave_sum(u2);
    float mean2 = u1 * (1.f / D);
    float var2  = u2 * (1.f / D) - mean2 * mean2;
    float rs2   = rsqrtf(var2 + EPS);
    *(float4*)&val1s[w * 520 + d]     = make_float4(y[0], y[1], y[2], y[3]);
    *(float4*)&val1s[w * 520 + d + 4] = make_float4(y[4], y[5], y[6], y[7]);
    uint4 pk;
    uint z0 = f2bf((y[0] - mean2) * rs2 * ln2g[d + 0] + ln2b[d + 0]);
    uint z1 = f2bf((y[1] - mean2) * rs2 * ln2g[d + 1] + ln2b[d + 1]);
    uint z2 = f2bf((y[2] - mean2) * rs2 * ln2g[d + 2] + ln2b[d + 2]);
    uint z3 = f2bf((y[3] - mean2) * rs2 * ln2g[d + 3] + ln2b[d + 3]);
    uint z4 = f2bf((y[4] - mean2) * rs2 * ln2g[d + 4] + ln2b[d + 4]);
    uint z5 = f2bf((y[5] - mean2) * rs2 * ln2g[d + 5] + ln2b[d + 5]);
    uint z6 = f2bf((y[6] - mean2) * rs2 * ln2g[d + 6] + ln2b[d + 6]);
    uint z7 = f2bf((y[7] - mean2) * rs2 * ln2g[d + 7] + ln2b[d + 7]);
    pk.x = z0 | (z1 << 16); pk.y = z2 | (z3 << 16);
    pk.z = z4 | (z5 << 16); pk.w = z6 | (z7 << 16);
    *(uint4*)&x2u[w * 528 + d] = pk;
  }
  __syncthreads();

  // ---- FFN1: h = gelu(x2 @ w1t^T + b1); rows 0..3 (replicated A); wave w
  // owns cols [w*256, w*256+256). B fragments direct from global (L2).
  for (int ct = 0; ct < 8; ++ct){
    int c0 = w * 256 + ct * 32;
    int c1 = c0 + 16;
    floatx4 f0 = {0.f,0.f,0.f,0.f}, f1 = {0.f,0.f,0.f,0.f};
#pragma unroll
    for (int s = 0; s < 16; ++s){
      short8 av = *(const short8*)&x2u[arow * 528 + s * 32 + q * 8];
      short8 b0 = *(const short8*)&w1l[(size_t)(c0 + lm) * 512 + s * 32 + q * 8];
      short8 b1 = *(const short8*)&w1l[(size_t)(c1 + lm) * 512 + s * 32 + q * 8];
      f0 = __builtin_amdgcn_mfma_f32_16x16x32_bf16(av, b0, f0, 0, 0, 0);
      f1 = __builtin_amdgcn_mfma_f32_16x16x32_bf16(av, b1, f1, 0, 0, 0);
    }
    if (q == 0){
#pragma unroll
      for (int r = 0; r < 4; ++r){
        float v0 = f0[r] + b1p[c0 + lm];
        float v1 = f1[r] + b1p[c1 + lm];
        v0 = 0.5f * v0 * (1.f + erff(v0 * 0.70710678118654752f));
        v1 = 0.5f * v1 * (1.f + erff(v1 * 0.70710678118654752f));
        hsu[r * 1040 + c0 + lm] = f2bf(v0);
        hsu[r * 1040 + c1 + lm] = f2bf(v1);
      }
    }
  }
  __syncthreads();

  // ---- FFN2: dst = h @ w2t^T + b2 + val1 (resid); wave w owns cols
  // [w*128, w*128+128). Writes next-layer val0 (f32+bf16) or final out.
  for (int ct = 0; ct < 4; ++ct){
    int c0 = w * 128 + ct * 32;
    int c1 = c0 + 16;
    floatx4 f0 = {0.f,0.f,0.f,0.f}, f1 = {0.f,0.f,0.f,0.f};
#pragma unroll
    for (int s = 0; s < 32; ++s){
      short8 av = *(const short8*)&hsu[arow * 1040 + s * 32 + q * 8];
      short8 b0 = *(const short8*)&w2l[(size_t)(c0 + lm) * 1024 + s * 32 + q * 8];
      short8 b1 = *(const short8*)&w2l[(size_t)(c1 + lm) * 1024 + s * 32 + q * 8];
      f0 = __builtin_amdgcn_mfma_f32_16x16x32_bf16(av, b0, f0, 0, 0, 0);
      f1 = __builtin_amdgcn_mfma_f32_16x16x32_bf16(av, b1, f1, 0, 0, 0);
    }
    if (q == 0){
#pragma unroll
      for (int r = 0; r < 4; ++r){
        int n = n0 + r;
        float v0 = f0[r] + b2p[c0 + lm] + val1s[r * 520 + c0 + lm];
        float v1 = f1[r] + b2p[c1 + lm] + val1s[r * 520 + c1 + lm];
        ushort h0 = f2bf(v0), h1 = f2bf(v1);
        if (n < N){
          dstf[(size_t)n * D + c0 + lm] = v0;
          dstf[(size_t)n * D + c1 + lm] = v1;
          if (!last){
            v0bfn[(size_t)n * D + c0 + lm] = h0;
            v0bfn[(size_t)n * D + c1 + lm] = h1;
          }
        }
        if (!last){
          v0u[r * 528 + c0 + lm] = h0;
          v0u[r * 528 + c1 + lm] = h1;
        }
      }
    }
  }

  // ---- next-layer QK projection for own rows (row-local, no halo)
  if (!last){
    __syncthreads();
    for (int ct = 0; ct < 2; ++ct){
      int c0 = w * 64 + ct * 32;
      int c1 = c0 + 16;
      floatx4 f0 = {0.f,0.f,0.f,0.f}, f1 = {0.f,0.f,0.f,0.f};
#pragma unroll
      for (int s = 0; s < 16; ++s){
        short8 av = *(const short8*)&v0u[arow * 528 + s * 32 + q * 8];
        short8 b0 = *(const short8*)&wqkn[(size_t)(c0 + lm) * 512 + s * 32 + q * 8];
        short8 b1 = *(const short8*)&wqkn[(size_t)(c1 + lm) * 512 + s * 32 + q * 8];
        f0 = __builtin_amdgcn_mfma_f32_16x16x32_bf16(av, b0, f0, 0, 0, 0);
        f1 = __builtin_amdgcn_mfma_f32_16x16x32_bf16(av, b1, f1, 0, 0, 0);
      }
      if (q == 0){
#pragma unroll
        for (int r = 0; r < 4; ++r){
          int n = n0 + r;
          if (n < N){
            qkn[(size_t)n * 256 + c0 + lm] = f2bf(f0[r]);
            qkn[(size_t)n * 256 + c1 + lm] = f2bf(f1[r]);
          }
        }
      }
    }
  }
}

} // anonymous namespace

extern "C" void kernel_launch(void* const* d_in, const int* in_sizes, int n_in,
                              void* d_out, int out_size, void* d_ws, size_t ws_size,
                              hipStream_t stream)
{
  (void)in_sizes; (void)n_in; (void)out_size; (void)ws_size;
  const int*   ids          = (const int*)d_in[0];
  const float* embed        = (const float*)d_in[1];
  const float* pos_emb      = (const float*)d_in[2];
  const float* ln_in_g      = (const float*)d_in[3];
  const float* ln_in_b      = (const float*)d_in[4];
  const float* anchor_state = (const float*)d_in[5];
  const float* anchor_val   = (const float*)d_in[6];
  const float* state_w      = (const float*)d_in[7];
  const float* state_b      = (const float*)d_in[8];
  const float* wq           = (const float*)d_in[9];
  const float* wk           = (const float*)d_in[10];
  const float* gate         = (const float*)d_in[11];
  const float* ln_g         = (const float*)d_in[12];
  const float* ln_b         = (const float*)d_in[13];
  const float* ffn_w1       = (const float*)d_in[14];
  const float* ffn_b1       = (const float*)d_in[15];
  const float* ffn_w2       = (const float*)d_in[16];
  const float* ffn_b2       = (const float*)d_in[17];
  const float* ln2_g        = (const float*)d_in[18];
  const float* ln2_b        = (const float*)d_in[19];
  float* out = (float*)d_out;

  float* wsf  = (float*)d_ws;
  float* val0a = wsf;  wsf += (size_t)N * D;     // layer input f32, buffer A
  float* val0b = wsf;  wsf += (size_t)N * D;     // buffer B
  ushort* wsu    = (ushort*)wsf;
  ushort* val0bfa = wsu;  wsu += (size_t)N * D;  // bf16 layer input A
  ushort* val0bfb = wsu;  wsu += (size_t)N * D;  // bf16 layer input B
  ushort* qka     = wsu;  wsu += (size_t)N * 256;
  ushort* qkb     = wsu;  wsu += (size_t)N * 256;
  ushort* wqkbf   = wsu;  wsu += (size_t)L * 256 * D;
  ushort* w1t     = wsu;  wsu += (size_t)L * HFF * D;
  ushort* w2t     = wsu;  wsu += (size_t)L * HFF * D;
  float* st0 = (float*)wsu;
  float* st1 = st0 + N;

  setup_kernel<<<GS2, 256, 0, stream>>>(
      ids, embed, pos_emb, ln_in_g, ln_in_b, anchor_val, anchor_state,
      state_w, state_b, val0a, val0bfa, st0,
      wq, wk, wqkbf, ffn_w1, ffn_w2, w1t, w2t);

  const int MT64 = (N + 63) / 64;
  gemm64<0><<<dim3(256 / 64, MT64), 256, 0, stream>>>(
      val0bfa, wqkbf, nullptr, nullptr, nullptr, qka, N, D, 256);

  float*  v0c  = val0a;  float*  v0n  = val0b;
  ushort* v0bc = val0bfa; ushort* v0bn = val0bfb;
  ushort* qkc  = qka;    ushort* qkn  = qkb;
  float*  sin_ = st0;    float*  sout_ = st1;

  for (int l = 0; l < L; ++l){
    int last = (l == L - 1);
    mega_kernel<<<NB4, 256, 0, stream>>>(
        qkc, last ? nullptr : (wqkbf + (size_t)(l + 1) * 256 * D),
        v0c, v0bc, sin_,
        last ? out : v0n, last ? nullptr : v0bn, last ? nullptr : qkn,
        sout_,
        gate + l, ln_g + l * D, ln_b + l * D, ln2_g + l * D, ln2_b + l * D,
        ffn_b1 + l * HFF, ffn_b2 + l * D,
        w1t + (size_t)l * HFF * D, w2t + (size_t)l * HFF * D, last);
    float*  tf = v0c;  v0c  = v0n;  v0n  = tf;
    ushort* tu = v0bc; v0bc = v0bn; v0bn = tu;
    tu = qkc; qkc = qkn; qkn = tu;
    float* ts = sin_; sin_ = sout_; sout_ = ts;
  }
}

// Round 9
// 372.261 us; speedup vs baseline: 1.9770x; 1.9770x over previous
//
#include <hip/hip_runtime.h>
#include <hip/hip_bf16.h>
#include <stdint.h>

namespace {

constexpr int D    = 512;
constexpr int S    = 1536;
constexpr int N    = S + 1;      // 1537
constexpr int L    = 4;
constexpr int H    = 4;
constexpr int R    = 32;
constexpr int W    = 128;
constexpr int HFF  = 1024;
constexpr float EPS = 1e-5f;

// attention: 4 tokens/block, shared neighbor span
constexpr int TB   = 4;
constexpr int NB4  = (N + TB - 1) / TB;   // 385 blocks
constexpr int SP   = 133;    // c=0..131 window span (g = n0-W+c), c=132 anchor
constexpr int SPAD = 137;    // padded row stride (2-way bank alias)

constexpr int GS2  = 1024;   // setup kernel grid
constexpr int SLABR = 528;   // gemm64 slab stride: 64 rows * 8 ushorts + 16 pad
constexpr int BK   = 128;    // gemm64 K-step

typedef __attribute__((ext_vector_type(8))) short short8;
typedef __attribute__((ext_vector_type(4))) float floatx4;

__device__ inline ushort f2bf(float x){
  __hip_bfloat16 h = __float2bfloat16(x);
  return *reinterpret_cast<ushort*>(&h);
}
__device__ inline float bf2f(uint u){
  union { uint u; float f; } c; c.u = u << 16; return c.f;
}

// ---------------- reductions ------------------------------------------------
__device__ inline float wave_sum(float v){
#pragma unroll
  for (int o = 32; o; o >>= 1) v += __shfl_xor(v, o, 64);
  return v;
}
__device__ inline float wave_max(float v){
#pragma unroll
  for (int o = 32; o; o >>= 1) v = fmaxf(v, __shfl_xor(v, o, 64));
  return v;
}
__device__ inline float block_sum(float v, float* scr){
  v = wave_sum(v);
  __syncthreads();
  if ((threadIdx.x & 63) == 0) scr[threadIdx.x >> 6] = v;
  __syncthreads();
  return scr[0] + scr[1] + scr[2] + scr[3];
}

// ---------------- fused setup: embed+LN+state | pack wqk | transpose ffn ----
__global__ __launch_bounds__(256) void setup_kernel(
    const int* __restrict__ ids, const float* __restrict__ embed,
    const float* __restrict__ pos, const float* __restrict__ g,
    const float* __restrict__ b, const float* __restrict__ anchor_val,
    const float* __restrict__ anchor_state, const float* __restrict__ state_w,
    const float* __restrict__ state_b, float* __restrict__ val,
    ushort* __restrict__ valbf, float* __restrict__ state,
    const float* __restrict__ wq, const float* __restrict__ wk,
    ushort* __restrict__ wqkbf,
    const float* __restrict__ ffn_w1, const float* __restrict__ ffn_w2,
    ushort* __restrict__ w1t, ushort* __restrict__ w2t)
{
  __shared__ float scr[4];
  __shared__ float tile[32 * 33];
  const int t = threadIdx.x;

  for (int n = blockIdx.x; n < N; n += GS2){
    if (n == 0){
      float a0 = anchor_val[t], a1 = anchor_val[t + 256];
      val[t] = a0; val[t + 256] = a1;
      valbf[t] = f2bf(a0); valbf[t + 256] = f2bf(a1);
      if (t == 0) state[0] = anchor_state[0];
      continue;
    }
    int tp = n - 1;
    int id = ids[tp];
    float x0 = embed[(size_t)id * D + t]       + pos[tp * D + t];
    float x1 = embed[(size_t)id * D + t + 256] + pos[tp * D + t + 256];
    float mean = block_sum(x0 + x1, scr) * (1.f / D);
    float var  = block_sum(x0 * x0 + x1 * x1, scr) * (1.f / D) - mean * mean;
    float rs   = rsqrtf(var + EPS);
    float y0 = (x0 - mean) * rs * g[t]       + b[t];
    float y1 = (x1 - mean) * rs * g[t + 256] + b[t + 256];
    val[n * D + t]       = y0;
    val[n * D + t + 256] = y1;
    valbf[n * D + t]       = f2bf(y0);
    valbf[n * D + t + 256] = f2bf(y1);
    float ts = block_sum(y0 * state_w[t] + y1 * state_w[t + 256], scr);
    if (t == 0) state[n] = ts + state_b[0];
  }

  for (int i = blockIdx.x * 256 + t; i < L * 256 * D; i += GS2 * 256){
    int d = i & 511;
    int c = (i >> 9) & 255;
    int l = i >> 17;
    int cc = c & 127;
    int h = cc >> 5, r = cc & 31;
    const float* src = (c < 128) ? wq : wk;
    wqkbf[i] = f2bf(src[((l * H + h) * D + d) * R + r]);
  }
  __syncthreads();

  const int tx = t & 31, ty = t >> 5;
  for (int tl = blockIdx.x; tl < 2 * L * 512; tl += GS2){
    const float* s; ushort* dd; int rows, cols, c0, r0;
    if (tl < 2048){
      int ll = tl >> 9, i = tl & 511;
      rows = D; cols = HFF;
      s  = ffn_w1 + (size_t)ll * D * HFF;
      dd = w1t   + (size_t)ll * D * HFF;
      c0 = (i & 31) << 5; r0 = (i >> 5) << 5;
    } else {
      int tl2 = tl - 2048;
      int ll = tl2 >> 9, i = tl2 & 511;
      rows = HFF; cols = D;
      s  = ffn_w2 + (size_t)ll * D * HFF;
      dd = w2t   + (size_t)ll * D * HFF;
      c0 = (i & 15) << 5; r0 = (i >> 4) << 5;
    }
    __syncthreads();
    for (int rr = ty; rr < 32; rr += 8)
      tile[rr * 33 + tx] = s[(size_t)(r0 + rr) * cols + c0 + tx];
    __syncthreads();
    for (int rr = ty; rr < 32; rr += 8)
      dd[(size_t)(c0 + rr) * rows + r0 + tx] = f2bf(tile[tx * 33 + rr]);
  }
}

// ---------------- bf16 MFMA GEMM, 64x64 tile, BK=128, 2-phase pipelined -----
// (R6-verified) C = act(A*Bt^T + bias)(+resid).
template<int ACT>
__global__ __launch_bounds__(256) void gemm64(
    const ushort* __restrict__ A, const ushort* __restrict__ Bt,
    const float* __restrict__ bias, const float* __restrict__ resid,
    float* __restrict__ C, ushort* __restrict__ Cbf,
    int M, int Kd, int Nc)
{
  __shared__ ushort As[16 * SLABR];
  __shared__ ushort Bs[16 * SLABR];
  const int row0 = blockIdx.y * 64;
  const int col0 = blockIdx.x * 64;
  const int t = threadIdx.x;
  const int lane = t & 63, w = t >> 6;
  const int wr = w & 1, wc = w >> 1;
  const int q = lane >> 4, lm = lane & 15;

  const int srow = t >> 3, skb = t & 7;
  int ar0 = min(row0 + srow,      M - 1);
  int ar1 = min(row0 + srow + 32, M - 1);
  const ushort* agA0 = A  + (size_t)ar0 * Kd + skb * 8;
  const ushort* agA1 = A  + (size_t)ar1 * Kd + skb * 8;
  const ushort* agB0 = Bt + (size_t)(col0 + srow) * Kd + skb * 8;
  const ushort* agB1 = Bt + (size_t)(col0 + srow + 32) * Kd + skb * 8;
  ushort* asw00 = &As[ skb      * SLABR +  srow       * 8];
  ushort* asw01 = &As[(skb + 8) * SLABR +  srow       * 8];
  ushort* asw10 = &As[ skb      * SLABR + (srow + 32) * 8];
  ushort* asw11 = &As[(skb + 8) * SLABR + (srow + 32) * 8];
  ushort* bsw00 = &Bs[ skb      * SLABR +  srow       * 8];
  ushort* bsw01 = &Bs[(skb + 8) * SLABR +  srow       * 8];
  ushort* bsw10 = &Bs[ skb      * SLABR + (srow + 32) * 8];
  ushort* bsw11 = &Bs[(skb + 8) * SLABR + (srow + 32) * 8];

  const ushort* arp = &As[(wr * 32 + lm) * 8];
  const ushort* brp = &Bs[(wc * 32 + lm) * 8];

  floatx4 acc[2][2];
#pragma unroll
  for (int m = 0; m < 2; ++m)
#pragma unroll
    for (int n = 0; n < 2; ++n) acc[m][n] = {0.f, 0.f, 0.f, 0.f};

  const int nk0 = Kd / BK;
  uint4 pa0, pa1, pa2, pa3, pb0, pb1, pb2, pb3;
  pa0 = *(const uint4*)(agA0);      pa1 = *(const uint4*)(agA0 + 64);
  pa2 = *(const uint4*)(agA1);      pa3 = *(const uint4*)(agA1 + 64);
  pb0 = *(const uint4*)(agB0);      pb1 = *(const uint4*)(agB0 + 64);
  pb2 = *(const uint4*)(agB1);      pb3 = *(const uint4*)(agB1 + 64);

  for (int i = 0; i < nk0; ++i){
    *(uint4*)asw00 = pa0; *(uint4*)asw01 = pa1;
    *(uint4*)asw10 = pa2; *(uint4*)asw11 = pa3;
    *(uint4*)bsw00 = pb0; *(uint4*)bsw01 = pb1;
    *(uint4*)bsw10 = pb2; *(uint4*)bsw11 = pb3;
    __syncthreads();
    if (i + 1 < nk0){
      const int ko = (i + 1) * BK;
      pa0 = *(const uint4*)(agA0 + ko);      pa1 = *(const uint4*)(agA0 + ko + 64);
      pa2 = *(const uint4*)(agA1 + ko);      pa3 = *(const uint4*)(agA1 + ko + 64);
      pb0 = *(const uint4*)(agB0 + ko);      pb1 = *(const uint4*)(agB0 + ko + 64);
      pb2 = *(const uint4*)(agB1 + ko);      pb3 = *(const uint4*)(agB1 + ko + 64);
    }
#pragma unroll
    for (int kk = 0; kk < 4; ++kk){
      const int kb = (kk * 4 + q) * SLABR;
      short8 am0 = *(const short8*)(arp + kb);
      short8 am1 = *(const short8*)(arp + kb + 16 * 8);
      short8 bn0 = *(const short8*)(brp + kb);
      short8 bn1 = *(const short8*)(brp + kb + 16 * 8);
      acc[0][0] = __builtin_amdgcn_mfma_f32_16x16x32_bf16(am0, bn0, acc[0][0], 0, 0, 0);
      acc[0][1] = __builtin_amdgcn_mfma_f32_16x16x32_bf16(am0, bn1, acc[0][1], 0, 0, 0);
      acc[1][0] = __builtin_amdgcn_mfma_f32_16x16x32_bf16(am1, bn0, acc[1][0], 0, 0, 0);
      acc[1][1] = __builtin_amdgcn_mfma_f32_16x16x32_bf16(am1, bn1, acc[1][1], 0, 0, 0);
    }
    __syncthreads();
  }

#pragma unroll
  for (int m = 0; m < 2; ++m){
#pragma unroll
    for (int n = 0; n < 2; ++n){
      int col = col0 + wc * 32 + n * 16 + lm;
#pragma unroll
      for (int r = 0; r < 4; ++r){
        int row = row0 + wr * 32 + m * 16 + q * 4 + r;
        if (row >= M) continue;
        float v = acc[m][n][r] + (bias ? bias[col] : 0.f);
        if (ACT == 1) v = 0.5f * v * (1.f + erff(v * 0.70710678118654752f));
        if (resid) v += resid[(size_t)row * Nc + col];
        size_t o = (size_t)row * Nc + col;
        if (C)   C[o] = v;
        if (Cbf) Cbf[o] = f2bf(v);
      }
    }
  }
}

// ---------------- attention, 4 tokens per block ------------------------------
// R9: d_val c-loop software-pipelined (depth-4 named-reg prefetch, prologue
// issued before the signed-softmax phase). Accumulation order unchanged
// (c ascending 0..132) -> bitwise-identical to the R6-verified kernel.
__global__ __launch_bounds__(256) void attn4_kernel(
    const ushort* __restrict__ qkbf, const float* __restrict__ val0,
    const ushort* __restrict__ val0bf, const float* __restrict__ state_in,
    float* __restrict__ val1, ushort* __restrict__ x2bf,
    float* __restrict__ state_out,
    const float* __restrict__ gate_p, const float* __restrict__ lng,
    const float* __restrict__ lnb, const float* __restrict__ ln2g,
    const float* __restrict__ ln2b)
{
  __shared__ float kg[64 * SPAD];   // [ch_local][c], reused as xbuf[4][520]
  __shared__ float qsh[TB * 128];
  __shared__ float ssh[16 * SPAD];  // [tok*4+h][c]
  __shared__ float ash[TB * SPAD];  // a then e, row per token
  const int n0 = blockIdx.x * TB;
  const int t = threadIdx.x;
  const int w = t >> 6, l = t & 63;   // wave = token index
  const float gate = gate_p[0];
  const float scale = 0.17677669529663687f;  // 1/sqrt(32)
  const int dv0 = 2 * t;              // d-offset for d_val / residual

  // ---- stage q (4 tokens x 128 ch)
#pragma unroll
  for (int i = t; i < TB * 128; i += 256){
    int it = i >> 7, ch = i & 127;
    int gr = min(n0 + it, N - 1);
    qsh[i] = bf2f((uint)qkbf[(size_t)gr * 256 + ch]);
  }

  // ---- scores, two halves of 64 channels
  for (int half = 0; half < 2; ++half){
    for (int i = t; i < SP * 16; i += 256){
      int c = i >> 4, c4 = i & 15;
      int g = (c == 132) ? 0 : min(max(n0 - W + c, 0), N - 1);
      uint2 v = *(const uint2*)&qkbf[(size_t)g * 256 + 128 + half * 64 + c4 * 4];
      int ch = c4 * 4;
      kg[(ch + 0) * SPAD + c] = bf2f(v.x & 0xffffu);
      kg[(ch + 1) * SPAD + c] = bf2f(v.x >> 16);
      kg[(ch + 2) * SPAD + c] = bf2f(v.y & 0xffffu);
      kg[(ch + 3) * SPAD + c] = bf2f(v.y >> 16);
    }
    __syncthreads();
    for (int tk = t; tk < TB * 2 * SP; tk += 256){
      int c = tk % SP;
      int th = tk / SP;            // 0..7
      int tok = th & 3, hh = th >> 2;
      int h = half * 2 + hh;
      const float* qs = &qsh[tok * 128 + h * 32];
      const float* ks = &kg[hh * 32 * SPAD + c];
      float acc = 0.f;
#pragma unroll
      for (int r = 0; r < 32; ++r) acc += qs[r] * ks[r * SPAD];
      ssh[(tok * 4 + h) * SPAD + c] = acc * scale;
    }
    __syncthreads();
  }

  // ---- per-(tok,c) head softmax -> a
  for (int i = t; i < TB * SP; i += 256){
    int tok = i / SP, c = i - tok * SP;
    const float* sr = &ssh[tok * 4 * SPAD + c];
    float s0 = sr[0], s1 = sr[SPAD], s2 = sr[2 * SPAD], s3 = sr[3 * SPAD];
    float a0 = fabsf(s0), a1 = fabsf(s1), a2 = fabsf(s2), a3 = fabsf(s3);
    float m = fmaxf(fmaxf(a0, a1), fmaxf(a2, a3));
    float w0 = expf(a0 - m), w1 = expf(a1 - m), w2 = expf(a2 - m), w3 = expf(a3 - m);
    ash[tok * SPAD + c] = (s0 * w0 + s1 * w1 + s2 * w2 + s3 * w3) / (w0 + w1 + w2 + w3);
  }
  __syncthreads();

  // ---- d_val prologue: issue first 4 span-row loads + anchor row early so
  // the signed-softmax shuffle chains hide their latency (they only touch
  // registers/global, not ash).
  uint p0, p1, p2, p3, pAr;
  {
    int ga = min(max(n0 - W + 0, 0), N - 1);
    int gb = min(max(n0 - W + 1, 0), N - 1);
    int gc = min(max(n0 - W + 2, 0), N - 1);
    int gd = min(max(n0 - W + 3, 0), N - 1);
    p0 = *(const uint*)&val0bf[(size_t)ga * D + dv0];
    p1 = *(const uint*)&val0bf[(size_t)gb * D + dv0];
    p2 = *(const uint*)&val0bf[(size_t)gc * D + dv0];
    p3 = *(const uint*)&val0bf[(size_t)gd * D + dv0];
    pAr = *(const uint*)&val0bf[dv0];          // c=132 anchor (row 0)
  }

  // ---- per-token signed softmax over span (wave w <-> token w), e in place
  {
    const int n = n0 + w;
    float* arow = &ash[w * SPAD];
    float a0 = arow[l];
    float a1 = arow[64 + l];
    float a2 = (l < 5) ? arow[128 + l] : 0.f;
    bool ok0 = (l >= w) && (n0 - W + l >= 0);
    bool ok1 = (n0 - W + 64 + l >= 0);
    bool ok2;
    if (l < 4)       ok2 = (l <= w);          // window col 128+l, g = n0+l >= 0
    else if (l == 4) ok2 = (n > W);           // anchor (c=132)
    else             ok2 = false;
    float cand = -3.4e38f;
    if (ok0) cand = fabsf(a0);
    if (ok1) cand = fmaxf(cand, fabsf(a1));
    if (ok2) cand = fmaxf(cand, fabsf(a2));
    float m = wave_max(cand);
    float e0 = ok0 ? expf(fabsf(a0) - m) : 0.f;
    float e1 = ok1 ? expf(fabsf(a1) - m) : 0.f;
    float e2 = ok2 ? expf(fabsf(a2) - m) : 0.f;
    float inv = 1.f / wave_sum(e0 + e1 + e2);
    int g0 = min(max(n0 - W + l, 0), N - 1);
    int g1 = min(max(n0 - W + 64 + l, 0), N - 1);
    int g2 = (l < 4) ? min(n0 + l, N - 1) : 0;
    float sg0 = (a0 > 0.f) ? 1.f : ((a0 < 0.f) ? -1.f : 0.f);
    float sg1 = (a1 > 0.f) ? 1.f : ((a1 < 0.f) ? -1.f : 0.f);
    float sg2 = (a2 > 0.f) ? 1.f : ((a2 < 0.f) ? -1.f : 0.f);
    float t0 = sg0 * e0 * inv * state_in[g0];
    float t1 = sg1 * e1 * inv * state_in[g1];
    float t2 = (l < 5) ? sg2 * e2 * inv * state_in[g2] : 0.f;
    arow[l] = t0;
    arow[64 + l] = t1;
    if (l < 5) arow[128 + l] = t2;
    float ds = wave_sum(t0 + t1 + t2);
    if (l == 0 && n < N) state_out[n] = state_in[n] + gate * ds;
  }
  __syncthreads();

  // ---- d_val: depth-4 pipelined stream over span rows (order c=0..132)
  float acc[TB][2];
#pragma unroll
  for (int k = 0; k < TB; ++k){ acc[k][0] = 0.f; acc[k][1] = 0.f; }
  for (int cb = 0; cb < 128; cb += 4){
    // prefetch chunk cb+4..cb+7 (max 131 < SP)
    int ga = min(max(n0 - W + cb + 4, 0), N - 1);
    int gb = min(max(n0 - W + cb + 5, 0), N - 1);
    int gc = min(max(n0 - W + cb + 6, 0), N - 1);
    int gd = min(max(n0 - W + cb + 7, 0), N - 1);
    uint q0 = *(const uint*)&val0bf[(size_t)ga * D + dv0];
    uint q1 = *(const uint*)&val0bf[(size_t)gb * D + dv0];
    uint q2 = *(const uint*)&val0bf[(size_t)gc * D + dv0];
    uint q3 = *(const uint*)&val0bf[(size_t)gd * D + dv0];
    {
      float vx = bf2f(p0 & 0xffffu), vy = bf2f(p0 >> 16);
#pragma unroll
      for (int k = 0; k < TB; ++k){
        float e = ash[k * SPAD + cb];
        acc[k][0] += e * vx; acc[k][1] += e * vy;
      }
    }
    {
      float vx = bf2f(p1 & 0xffffu), vy = bf2f(p1 >> 16);
#pragma unroll
      for (int k = 0; k < TB; ++k){
        float e = ash[k * SPAD + cb + 1];
        acc[k][0] += e * vx; acc[k][1] += e * vy;
      }
    }
    {
      float vx = bf2f(p2 & 0xffffu), vy = bf2f(p2 >> 16);
#pragma unroll
      for (int k = 0; k < TB; ++k){
        float e = ash[k * SPAD + cb + 2];
        acc[k][0] += e * vx; acc[k][1] += e * vy;
      }
    }
    {
      float vx = bf2f(p3 & 0xffffu), vy = bf2f(p3 >> 16);
#pragma unroll
      for (int k = 0; k < TB; ++k){
        float e = ash[k * SPAD + cb + 3];
        acc[k][0] += e * vx; acc[k][1] += e * vy;
      }
    }
    p0 = q0; p1 = q1; p2 = q2; p3 = q3;
  }
  // residual loads issued here, hidden under the epilogue FMAs
  float2 rv0, rv1, rv2, rv3;
  {
    int nc0 = min(n0 + 0, N - 1), nc1 = min(n0 + 1, N - 1);
    int nc2 = min(n0 + 2, N - 1), nc3 = min(n0 + 3, N - 1);
    rv0 = *(const float2*)&val0[(size_t)nc0 * D + dv0];
    rv1 = *(const float2*)&val0[(size_t)nc1 * D + dv0];
    rv2 = *(const float2*)&val0[(size_t)nc2 * D + dv0];
    rv3 = *(const float2*)&val0[(size_t)nc3 * D + dv0];
  }
  // epilogue: c = 128..131 (in p0..p3), then c = 132 (anchor)
  {
    float vx = bf2f(p0 & 0xffffu), vy = bf2f(p0 >> 16);
#pragma unroll
    for (int k = 0; k < TB; ++k){
      float e = ash[k * SPAD + 128];
      acc[k][0] += e * vx; acc[k][1] += e * vy;
    }
  }
  {
    float vx = bf2f(p1 & 0xffffu), vy = bf2f(p1 >> 16);
#pragma unroll
    for (int k = 0; k < TB; ++k){
      float e = ash[k * SPAD + 129];
      acc[k][0] += e * vx; acc[k][1] += e * vy;
    }
  }
  {
    float vx = bf2f(p2 & 0xffffu), vy = bf2f(p2 >> 16);
#pragma unroll
    for (int k = 0; k < TB; ++k){
      float e = ash[k * SPAD + 130];
      acc[k][0] += e * vx; acc[k][1] += e * vy;
    }
  }
  {
    float vx = bf2f(p3 & 0xffffu), vy = bf2f(p3 >> 16);
#pragma unroll
    for (int k = 0; k < TB; ++k){
      float e = ash[k * SPAD + 131];
      acc[k][0] += e * vx; acc[k][1] += e * vy;
    }
  }
  {
    float vx = bf2f(pAr & 0xffffu), vy = bf2f(pAr >> 16);
#pragma unroll
    for (int k = 0; k < TB; ++k){
      float e = ash[k * SPAD + 132];
      acc[k][0] += e * vx; acc[k][1] += e * vy;
    }
  }
  // residual into xbuf (reuse kg; kg dead after scores)
  float* xbuf = kg;    // [4][520]
  xbuf[0 * 520 + dv0]     = rv0.x + gate * acc[0][0];
  xbuf[0 * 520 + dv0 + 1] = rv0.y + gate * acc[0][1];
  xbuf[1 * 520 + dv0]     = rv1.x + gate * acc[1][0];
  xbuf[1 * 520 + dv0 + 1] = rv1.y + gate * acc[1][1];
  xbuf[2 * 520 + dv0]     = rv2.x + gate * acc[2][0];
  xbuf[2 * 520 + dv0 + 1] = rv2.y + gate * acc[2][1];
  xbuf[3 * 520 + dv0]     = rv3.x + gate * acc[3][0];
  xbuf[3 * 520 + dv0 + 1] = rv3.y + gate * acc[3][1];
  __syncthreads();

  // ---- LN1 -> val1, LN2 -> x2bf (wave per token, 8 dims per lane)
  {
    const int n = n0 + w;
    const int d = l * 8;
    const float* xr = &xbuf[w * 520 + d];
    float x[8];
#pragma unroll
    for (int j = 0; j < 8; ++j) x[j] = xr[j];
    float s1 = 0.f, s2 = 0.f;
#pragma unroll
    for (int j = 0; j < 8; ++j){ s1 += x[j]; s2 += x[j] * x[j]; }
    s1 = wave_sum(s1); s2 = wave_sum(s2);
    float mean = s1 * (1.f / D);
    float var  = s2 * (1.f / D) - mean * mean;
    float rs   = rsqrtf(var + EPS);
    float y[8];
    float u1 = 0.f, u2 = 0.f;
#pragma unroll
    for (int j = 0; j < 8; ++j){
      float yv = (x[j] - mean) * rs * lng[d + j] + lnb[d + j];
      y[j] = yv; u1 += yv; u2 += yv * yv;
    }
    u1 = wave_sum(u1); u2 = wave_sum(u2);
    float mean2 = u1 * (1.f / D);
    float var2  = u2 * (1.f / D) - mean2 * mean2;
    float rs2   = rsqrtf(var2 + EPS);
    if (n < N){
      *(float4*)&val1[(size_t)n * D + d]     = make_float4(y[0], y[1], y[2], y[3]);
      *(float4*)&val1[(size_t)n * D + d + 4] = make_float4(y[4], y[5], y[6], y[7]);
      uint4 pk;
      uint z0 = f2bf((y[0] - mean2) * rs2 * ln2g[d + 0] + ln2b[d + 0]);
      uint z1 = f2bf((y[1] - mean2) * rs2 * ln2g[d + 1] + ln2b[d + 1]);
      uint z2 = f2bf((y[2] - mean2) * rs2 * ln2g[d + 2] + ln2b[d + 2]);
      uint z3 = f2bf((y[3] - mean2) * rs2 * ln2g[d + 3] + ln2b[d + 3]);
      uint z4 = f2bf((y[4] - mean2) * rs2 * ln2g[d + 4] + ln2b[d + 4]);
      uint z5 = f2bf((y[5] - mean2) * rs2 * ln2g[d + 5] + ln2b[d + 5]);
      uint z6 = f2bf((y[6] - mean2) * rs2 * ln2g[d + 6] + ln2b[d + 6]);
      uint z7 = f2bf((y[7] - mean2) * rs2 * ln2g[d + 7] + ln2b[d + 7]);
      pk.x = z0 | (z1 << 16); pk.y = z2 | (z3 << 16);
      pk.z = z4 | (z5 << 16); pk.w = z6 | (z7 << 16);
      *(uint4*)&x2bf[(size_t)n * D + d] = pk;
    }
  }
}

} // anonymous namespace

extern "C" void kernel_launch(void* const* d_in, const int* in_sizes, int n_in,
                              void* d_out, int out_size, void* d_ws, size_t ws_size,
                              hipStream_t stream)
{
  (void)in_sizes; (void)n_in; (void)out_size; (void)ws_size;
  const int*   ids          = (const int*)d_in[0];
  const float* embed        = (const float*)d_in[1];
  const float* pos_emb      = (const float*)d_in[2];
  const float* ln_in_g      = (const float*)d_in[3];
  const float* ln_in_b      = (const float*)d_in[4];
  const float* anchor_state = (const float*)d_in[5];
  const float* anchor_val   = (const float*)d_in[6];
  const float* state_w      = (const float*)d_in[7];
  const float* state_b      = (const float*)d_in[8];
  const float* wq           = (const float*)d_in[9];
  const float* wk           = (const float*)d_in[10];
  const float* gate         = (const float*)d_in[11];
  const float* ln_g         = (const float*)d_in[12];
  const float* ln_b         = (const float*)d_in[13];
  const float* ffn_w1       = (const float*)d_in[14];
  const float* ffn_b1       = (const float*)d_in[15];
  const float* ffn_w2       = (const float*)d_in[16];
  const float* ffn_b2       = (const float*)d_in[17];
  const float* ln2_g        = (const float*)d_in[18];
  const float* ln2_b        = (const float*)d_in[19];
  float* out = (float*)d_out;

  float* wsf  = (float*)d_ws;
  float* val0 = wsf;  wsf += (size_t)N * D;      // layer input fp32 (residual)
  float* val1 = wsf;  wsf += (size_t)N * D;      // post-attn+LN1 (FFN2 residual)
  ushort* wsu   = (ushort*)wsf;
  ushort* val0bf = wsu;  wsu += (size_t)N * D;   // bf16 layer input
  ushort* x2bf   = wsu;  wsu += (size_t)N * D;   // bf16 LN2 out (FFN1 A)
  ushort* hbf    = wsu;  wsu += (size_t)N * HFF; // bf16 gelu out (FFN2 A)
  ushort* qkbf   = wsu;  wsu += (size_t)N * 256; // bf16 q|k per token
  ushort* wqkbf  = wsu;  wsu += (size_t)L * 256 * D;
  ushort* w1t    = wsu;  wsu += (size_t)L * HFF * D;
  ushort* w2t    = wsu;  wsu += (size_t)L * HFF * D;
  float* st0 = (float*)wsu;
  float* st1 = st0 + N;

  setup_kernel<<<GS2, 256, 0, stream>>>(
      ids, embed, pos_emb, ln_in_g, ln_in_b, anchor_val, anchor_state,
      state_w, state_b, val0, val0bf, st0,
      wq, wk, wqkbf, ffn_w1, ffn_w2, w1t, w2t);

  float* sin_  = st0;
  float* sout_ = st1;
  const int MT64 = (N + 63) / 64;   // 25 row tiles
  for (int l = 0; l < L; ++l){
    gemm64<0><<<dim3(256 / 64, MT64), 256, 0, stream>>>(
        val0bf, wqkbf + (size_t)l * 256 * D, nullptr, nullptr,
        nullptr, qkbf, N, D, 256);
    attn4_kernel<<<NB4, 256, 0, stream>>>(qkbf, val0, val0bf, sin_, val1, x2bf,
                                          sout_, gate + l, ln_g + l * D,
                                          ln_b + l * D, ln2_g + l * D,
                                          ln2_b + l * D);
    gemm64<1><<<dim3(HFF / 64, MT64), 256, 0, stream>>>(
        x2bf, w1t + (size_t)l * HFF * D, ffn_b1 + l * HFF, nullptr,
        nullptr, hbf, N, D, HFF);
    float* dst = (l == L - 1) ? out : val0;
    gemm64<0><<<dim3(D / 64, MT64), 256, 0, stream>>>(
        hbf, w2t + (size_t)l * HFF * D, ffn_b2 + l * D, val1,
        dst, val0bf, N, HFF, D);
    float* tmp = sin_; sin_ = sout_; sout_ = tmp;
  }
}